// Round 4
// baseline (180.169 us; speedup 1.0000x reference)
//
#include <hip/hip_runtime.h>
#include <stdint.h>

// CropConv via implicit GEMM + MFMA (bf16 in, fp32 accum).
//   M=64 (oc), K=576 (ic*3*3), N=262144 (b*h*w)
// R4: conv uses 32 KiB LDS (two 32-ic K-phases, single buffer) -> 4 blocks/CU
//     = 4 waves/SIMD to hide A-load (L2) latency; XCD-swizzled block ids.
//     Prepass reads float4 (1 KB/instr) instead of scalar gather.

#define B_ 16
#define C_ 64
#define H_ 128
#define W_ 128
#define HP 130
#define WP 130

typedef float f32x4 __attribute__((ext_vector_type(4)));
typedef short bf16x8 __attribute__((ext_vector_type(8)));

__device__ inline unsigned short f2bf(float f) {
    union { float f; uint32_t u; } v; v.f = f;
    uint32_t u = v.u + 0x7FFF + ((v.u >> 16) & 1);   // RNE
    return (unsigned short)(u >> 16);
}

// ---- pre-pass: weights [oc][ic][3][3] fp32 -> [kk][oc][ic] bf16 ----
__global__ __launch_bounds__(256) void xform_weight(
    const float* __restrict__ wgt, uint16_t* __restrict__ Wb)
{
    int idx = blockIdx.x * 256 + threadIdx.x;     // < 36864
    int kk  = idx >> 12;
    int rem = idx & 4095;
    int oc  = rem >> 6, ic = rem & 63;
    Wb[idx] = f2bf(wgt[((size_t)oc * 64 + ic) * 9 + kk]);
}

// ---- pre-pass: x [b][ic][h][w] fp32 -> X' [b][h'][w'][ic] bf16 + halo ----
// thread = (8 ic) x (4 w): float4 loads, dwordx4 stores, 1 KB/instr coalescing.
__global__ __launch_bounds__(256) void xform_input_fused(
    const float* __restrict__ x, uint32_t* __restrict__ Xu)
{
    const int t  = threadIdx.x;
    const int hp = blockIdx.x;                    // padded row 0..129
    const int b  = blockIdx.y;
    uint4* rowbase = (uint4*)(Xu + ((size_t)(b * HP + hp)) * WP * 32);

    if (hp == 0 || hp == HP - 1) {                // halo row: zero 1040 uint4
        uint4 z; z.x = z.y = z.z = z.w = 0;
        for (int k = t; k < WP * 8; k += 256) rowbase[k] = z;
        return;
    }
    if (t < 16) {                                 // halo cols 0 and 129
        uint4 z; z.x = z.y = z.z = z.w = 0;
        int c = (t < 8) ? 0 : (WP - 1);
        rowbase[c * 8 + (t & 7)] = z;
    }
    const int h   = hp - 1;
    const int w4  = t >> 3;                       // 0..31
    const int icg = t & 7;                        // 0..7  (ic = icg*8 .. +7)
    const int w   = w4 * 4;

    const float* xb = x + (((size_t)(b * C_ + icg * 8)) * H_ + h) * W_ + w;
    float4 v[8];
    #pragma unroll
    for (int j = 0; j < 8; ++j)
        v[j] = *(const float4*)(xb + (size_t)j * (H_ * W_));

    uint4* dst = rowbase + ((size_t)(w + 1)) * 8 + icg;
    const float* vp = (const float*)v;            // v[j][jw] = vp[j*4+jw]
    #pragma unroll
    for (int jw = 0; jw < 4; ++jw) {
        uint32_t uu[4];
        #pragma unroll
        for (int k = 0; k < 4; ++k)
            uu[k] = (uint32_t)f2bf(vp[(2 * k) * 4 + jw]) |
                    ((uint32_t)f2bf(vp[(2 * k + 1) * 4 + jw]) << 16);
        dst[jw * 8] = *(uint4*)uu;
    }
}

// ---- main: LDS-staged implicit GEMM, 32 KiB LDS, 2 K-phases ----
// grid (64, 16) XCD-swizzled; block 256 = 4 waves.
// wave wv: h = 2*htile + (wv>>1), w-range (wv&1)*64..+64; 4m x 4n MFMA tiles.
// LDS per phase: [r:4][c:128][j':4] uint4 (32 ic), j' = (j + c) & 3 swizzle.
__global__ __launch_bounds__(256, 4) void conv_mfma(
    const uint4* __restrict__ Wq,   // [9][64][8] uint4
    const uint4* __restrict__ Xq,   // [16][130][130][8] uint4
    float* __restrict__ out)
{
    __shared__ uint4 smem[2048];    // 32 KiB

    const int t    = threadIdx.x;
    const int lane = t & 63;
    const int wv   = t >> 6;
    const int n    = lane & 15;
    const int q    = lane >> 4;

    // XCD swizzle: each XCD gets 2 full batches, all h-tiles contiguous.
    const int id    = blockIdx.x + (blockIdx.y << 6);       // 0..1023
    const int vid   = ((id & 7) << 7) | (id >> 3);
    const int htile = vid & 63;
    const int b     = vid >> 6;

    const int h0 = htile * 2;
    const int h  = h0 + (wv >> 1);
    const int wb = (wv & 1) * 64;

    f32x4 acc[4][4];
    #pragma unroll
    for (int i = 0; i < 4; ++i)
        #pragma unroll
        for (int tt = 0; tt < 4; ++tt)
            acc[i][tt] = (f32x4){0.f, 0.f, 0.f, 0.f};

    const int aB = n * 8 + q;                 // Wq uint4 base
    const bool lz = (wb + n) == 0;            // col -1 lane (kw=0, tt=0)
    const bool rz = (wb + n) == 79;           // col 128 lane (kw=2, tt=3)
    const bf16x8 zfrag = 0;
    const uint4* src = Xq + (size_t)(b * HP + h0) * WP * 8;

    #pragma unroll
    for (int ch = 0; ch < 2; ++ch) {
        if (ch) __syncthreads();              // protect smem reuse
        // stage rows h0..h0+3 (padded), cols 1..128, ic chunk ch*32..+31.
        // wave wv stages row r=wv: 512 uint4 = 8 wave-ops of 64.
        #pragma unroll
        for (int o = 0; o < 8; ++o) {
            int s  = (wv << 9) | (o << 6) | lane;   // LDS uint4 slot
            int r  = s >> 9;                        // == wv
            int c  = (s >> 2) & 127;
            int jp = s & 3;
            int j  = (jp - c) & 3;
            const uint4* g = src + (size_t)(r * WP + c + 1) * 8 + ch * 4 + j;
            __builtin_amdgcn_global_load_lds(
                (const __attribute__((address_space(1))) uint32_t*)g,
                (__attribute__((address_space(3))) uint32_t*)&smem[(wv << 9) | (o << 6)],
                16, 0, 0);
        }
        __syncthreads();

        #pragma unroll
        for (int kh = 0; kh < 3; ++kh) {
            const int row = (wv >> 1) + kh;   // LDS row 0..3
            #pragma unroll
            for (int kw = 0; kw < 3; ++kw) {
                const int kk = kh * 3 + kw;
                bf16x8 a[4], bb[4];
                #pragma unroll
                for (int i = 0; i < 4; ++i)
                    a[i] = __builtin_bit_cast(bf16x8,
                        Wq[aB + kk * 512 + i * 128 + ch * 4]);
                #pragma unroll
                for (int tt = 0; tt < 4; ++tt) {
                    int c  = wb + tt * 16 + n + kw - 1;     // -1..128
                    int cc = min(max(c, 0), 127);
                    int slot = ((row * 128 + cc) << 2) | ((q + cc) & 3);
                    bf16x8 v = __builtin_bit_cast(bf16x8, smem[slot]);
                    if (kw == 0 && tt == 0) v = lz ? zfrag : v;
                    if (kw == 2 && tt == 3) v = rz ? zfrag : v;
                    bb[tt] = v;
                }
                #pragma unroll
                for (int i = 0; i < 4; ++i)
                    #pragma unroll
                    for (int tt = 0; tt < 4; ++tt)
                        acc[i][tt] = __builtin_amdgcn_mfma_f32_16x16x32_bf16(
                            a[i], bb[tt], acc[i][tt], 0, 0, 0);
            }
        }
    }

    // epilogue: oc = i*16 + q*4 + r, w = wb + tt*16 + n
    const bool hz = (h >= 44 && h < 84);
    #pragma unroll
    for (int i = 0; i < 4; ++i) {
        #pragma unroll
        for (int tt = 0; tt < 4; ++tt) {
            const int w0 = wb + tt * 16 + n;
            const bool zz = hz && (w0 >= 44 && w0 < 84);
            #pragma unroll
            for (int r = 0; r < 4; ++r) {
                const int oc = i * 16 + q * 4 + r;
                out[(((size_t)b * C_ + oc) * H_ + h) * W_ + w0] =
                    zz ? 0.f : acc[i][tt][r];
            }
        }
    }
}

// ---- fallback (round-1 direct conv) if ws too small ----
__global__ __launch_bounds__(256) void cropconv_direct(
    const float* __restrict__ x, const float* __restrict__ wgt,
    float* __restrict__ out)
{
    const int ocpair = blockIdx.x, ht = blockIdx.y, b = blockIdx.z;
    const int oc0 = ocpair * 2, h0 = ht * 8;
    const int t = threadIdx.x, w = t & 127, hl = (t >> 7) * 4;
    __shared__ float sm[10][128];
    float acc[2][4];
    #pragma unroll
    for (int i = 0; i < 2; ++i)
        #pragma unroll
        for (int j = 0; j < 4; ++j) acc[i][j] = 0.f;
    const float* xb  = x + (size_t)b * C_ * H_ * W_;
    const float* wp0 = wgt + (size_t)oc0 * C_ * 9;
    const float* wp1 = wp0 + (size_t)C_ * 9;
    for (int ic = 0; ic < C_; ++ic) {
        const float* xc = xb + (size_t)ic * H_ * W_;
        __syncthreads();
        #pragma unroll
        for (int k = 0; k < 5; ++k) {
            int idx = t + k * 256, r = idx >> 7, c = idx & 127, gr = h0 - 1 + r;
            sm[r][c] = (gr >= 0 && gr < H_) ? xc[gr * W_ + c] : 0.f;
        }
        __syncthreads();
        float wa[9], wbv[9];
        #pragma unroll
        for (int qq = 0; qq < 9; ++qq) { wa[qq] = wp0[ic*9+qq]; wbv[qq] = wp1[ic*9+qq]; }
        float in[6][3];
        #pragma unroll
        for (int r = 0; r < 6; ++r) {
            int rr = hl + r;
            in[r][0] = (w > 0)   ? sm[rr][w-1] : 0.f;
            in[r][1] =             sm[rr][w];
            in[r][2] = (w < 127) ? sm[rr][w+1] : 0.f;
        }
        #pragma unroll
        for (int j = 0; j < 4; ++j)
            #pragma unroll
            for (int dh = 0; dh < 3; ++dh)
                #pragma unroll
                for (int dw = 0; dw < 3; ++dw) {
                    float v = in[j+dh][dw];
                    acc[0][j] = fmaf(v, wa[dh*3+dw], acc[0][j]);
                    acc[1][j] = fmaf(v, wbv[dh*3+dw], acc[1][j]);
                }
    }
    const bool win_w = (w >= 44 && w < 84);
    #pragma unroll
    for (int i = 0; i < 2; ++i) {
        float* ob = out + (((size_t)b * C_ + (oc0+i)) * H_ + h0) * (size_t)W_;
        #pragma unroll
        for (int j = 0; j < 4; ++j) {
            int h = h0 + hl + j;
            ob[(hl+j) * W_ + w] = (win_w && h >= 44 && h < 84) ? 0.f : acc[i][j];
        }
    }
}

extern "C" void kernel_launch(void* const* d_in, const int* in_sizes, int n_in,
                              void* d_out, int out_size, void* d_ws, size_t ws_size,
                              hipStream_t stream) {
    const float* x   = (const float*)d_in[0];
    const float* wgt = (const float*)d_in[1];
    float* out       = (float*)d_out;

    const size_t W_BYTES = 9 * 64 * 64 * 2;                        // 73,728
    const size_t X_BYTES = (size_t)B_ * HP * WP * 64 * 2;          // 34,611,200
    if (ws_size >= W_BYTES + X_BYTES) {
        uint16_t* Wb = (uint16_t*)d_ws;
        uint32_t* Xu = (uint32_t*)((char*)d_ws + W_BYTES);
        xform_weight<<<dim3(144), dim3(256), 0, stream>>>(wgt, Wb);
        xform_input_fused<<<dim3(130, 16), dim3(256), 0, stream>>>(x, Xu);
        conv_mfma<<<dim3(64, 16), dim3(256), 0, stream>>>(
            (const uint4*)Wb, (const uint4*)Xu, out);
    } else {
        cropconv_direct<<<dim3(32, 16, 16), dim3(256), 0, stream>>>(x, wgt, out);
    }
}

// Round 5
// 173.950 us; speedup vs baseline: 1.0357x; 1.0357x over previous
//
#include <hip/hip_runtime.h>
#include <stdint.h>

// CropConv via implicit GEMM + MFMA (bf16 in, fp32 accum), R5:
// NO input prepass — conv reads x (NCHW fp32) directly, converts to bf16
// in-register (add 0x8000 + v_perm hi16 pack), stages to LDS.
// Two 32-ic K-phases over a single 40 KiB LDS buffer:
//   slot(r,c,j) = (r*128 + c)*5 + j   (uint4 granules; stride 5 is coprime
//   with 8 bank-groups -> reads 2-way (free), writes balanced 8/group).
// 4 blocks/CU (160 KiB LDS exactly), __launch_bounds__(256,4).
// Only remaining prepass: weights -> bf16 [kk][oc][ic] (73,728 B in ws).

#define B_ 16
#define C_ 64
#define H_ 128
#define W_ 128

typedef float f32x4 __attribute__((ext_vector_type(4)));
typedef short bf16x8 __attribute__((ext_vector_type(8)));

__device__ inline unsigned short f2bf(float f) {
    union { float f; uint32_t u; } v; v.f = f;
    uint32_t u = v.u + 0x7FFF + ((v.u >> 16) & 1);   // RNE
    return (unsigned short)(u >> 16);
}

// ---- pre-pass: weights [oc][ic][3][3] fp32 -> [kk][oc][ic] bf16 ----
__global__ __launch_bounds__(256) void xform_weight(
    const float* __restrict__ wgt, uint16_t* __restrict__ Wb)
{
    int idx = blockIdx.x * 256 + threadIdx.x;     // < 36864
    int kk  = idx >> 12;
    int rem = idx & 4095;
    int oc  = rem >> 6, ic = rem & 63;
    Wb[idx] = f2bf(wgt[((size_t)oc * 64 + ic) * 9 + kk]);
}

// ---- main: fused convert + LDS-staged implicit GEMM ----
// grid (64, 16) XCD-swizzled; block 256 = 4 waves.
// wave wv: h = 2*htile + (wv>>1), w-range (wv&1)*64..+64; 4m x 4n MFMA tiles.
__global__ __launch_bounds__(256, 4) void conv_mfma(
    const uint4* __restrict__ Wq,   // [9][64][8] uint4 (bf16 weights)
    const float* __restrict__ x,    // [16][64][128][128] fp32
    float* __restrict__ out)
{
    __shared__ uint4 smem[2560];    // 40 KiB; slot = (r*128+c)*5 + j

    const int t    = threadIdx.x;
    const int lane = t & 63;
    const int wv   = t >> 6;
    const int n    = lane & 15;
    const int q    = lane >> 4;

    // XCD swizzle: consecutive vids on one XCD -> adjacent htiles share rows.
    const int id    = blockIdx.x + (blockIdx.y << 6);       // 0..1023
    const int vid   = ((id & 7) << 7) | (id >> 3);
    const int htile = vid & 63;
    const int b     = vid >> 6;

    const int h0 = htile * 2;
    const int h  = h0 + (wv >> 1);
    const int wb = (wv & 1) * 64;

    f32x4 acc[4][4];
    #pragma unroll
    for (int i = 0; i < 4; ++i)
        #pragma unroll
        for (int tt = 0; tt < 4; ++tt)
            acc[i][tt] = (f32x4){0.f, 0.f, 0.f, 0.f};

    const int aB = n * 8 + q;                 // Wq uint4 base
    const bool lz = (wb + n) == 0;            // col -1 lane (kw=0, tt=0)
    const bool rz = (wb + n) == 79;           // col 128 lane (kw=2, tt=3)
    const bf16x8 zfrag = 0;

    #pragma unroll
    for (int ch = 0; ch < 2; ++ch) {
        if (ch) __syncthreads();              // phase-0 reads done before restage

        // ---- stage: rows h0-1..h0+2, ic ch*32..+31, fp32 -> bf16 ----
        // unit = t + 256u: r = unit>>7 (wave-uniform), w4 = (unit>>2)&31,
        // icg = unit&3 (8 consecutive ic). 8 float4 loads -> 4 uint4 packs.
        #pragma unroll
        for (int u = 0; u < 2; ++u) {
            const int unit = t + (u << 8);
            const int r    = unit >> 7;
            const int w4   = (unit >> 2) & 31;
            const int icg  = unit & 3;
            const int hin  = h0 - 1 + r;
            uint4 val[4];
            if (hin >= 0 && hin < H_) {
                const float* xp = x +
                    (((size_t)b * C_ + (ch * 32 + icg * 8)) * H_ + hin) * W_ + w4 * 4;
                uint32_t vb[8][4];
                #pragma unroll
                for (int e = 0; e < 8; ++e) {
                    float4 v = *(const float4*)(xp + (size_t)e * (H_ * W_));
                    vb[e][0] = __float_as_uint(v.x) + 0x8000u;   // round-half-up
                    vb[e][1] = __float_as_uint(v.y) + 0x8000u;
                    vb[e][2] = __float_as_uint(v.z) + 0x8000u;
                    vb[e][3] = __float_as_uint(v.w) + 0x8000u;
                }
                #pragma unroll
                for (int jw = 0; jw < 4; ++jw) {
                    // out = hi16(even) | hi16(odd)<<16  (ic ascending)
                    uint32_t p0 = __builtin_amdgcn_perm(vb[1][jw], vb[0][jw], 0x07060302u);
                    uint32_t p1 = __builtin_amdgcn_perm(vb[3][jw], vb[2][jw], 0x07060302u);
                    uint32_t p2 = __builtin_amdgcn_perm(vb[5][jw], vb[4][jw], 0x07060302u);
                    uint32_t p3 = __builtin_amdgcn_perm(vb[7][jw], vb[6][jw], 0x07060302u);
                    val[jw] = (uint4){p0, p1, p2, p3};
                }
            } else {
                #pragma unroll
                for (int jw = 0; jw < 4; ++jw) val[jw] = (uint4){0u, 0u, 0u, 0u};
            }
            #pragma unroll
            for (int jw = 0; jw < 4; ++jw)
                smem[(r * 128 + w4 * 4 + jw) * 5 + icg] = val[jw];
        }
        __syncthreads();

        // ---- compute: 9 kk x 16 MFMA on this 32-ic chunk ----
        #pragma unroll
        for (int kh = 0; kh < 3; ++kh) {
            const int row = (wv >> 1) + kh;   // LDS row 0..3
            #pragma unroll
            for (int kw = 0; kw < 3; ++kw) {
                const int kk = kh * 3 + kw;
                bf16x8 a[4], bb[4];
                #pragma unroll
                for (int i = 0; i < 4; ++i)
                    a[i] = __builtin_bit_cast(bf16x8,
                        Wq[aB + kk * 512 + i * 128 + ch * 4]);
                #pragma unroll
                for (int tt = 0; tt < 4; ++tt) {
                    int c  = wb + tt * 16 + n + kw - 1;     // -1..128
                    int cc = min(max(c, 0), 127);
                    bf16x8 v = __builtin_bit_cast(bf16x8,
                        smem[(row * 128 + cc) * 5 + q]);
                    if (kw == 0 && tt == 0) v = lz ? zfrag : v;
                    if (kw == 2 && tt == 3) v = rz ? zfrag : v;
                    bb[tt] = v;
                }
                #pragma unroll
                for (int i = 0; i < 4; ++i)
                    #pragma unroll
                    for (int tt = 0; tt < 4; ++tt)
                        acc[i][tt] = __builtin_amdgcn_mfma_f32_16x16x32_bf16(
                            a[i], bb[tt], acc[i][tt], 0, 0, 0);
            }
        }
    }

    // epilogue: oc = i*16 + q*4 + r, w = wb + tt*16 + n
    const bool hz = (h >= 44 && h < 84);
    #pragma unroll
    for (int i = 0; i < 4; ++i) {
        #pragma unroll
        for (int tt = 0; tt < 4; ++tt) {
            const int w0 = wb + tt * 16 + n;
            const bool zz = hz && (w0 >= 44 && w0 < 84);
            #pragma unroll
            for (int r = 0; r < 4; ++r) {
                const int oc = i * 16 + q * 4 + r;
                out[(((size_t)b * C_ + oc) * H_ + h) * W_ + w0] =
                    zz ? 0.f : acc[i][tt][r];
            }
        }
    }
}

// ---- fallback (round-1 direct conv) if ws too small ----
__global__ __launch_bounds__(256) void cropconv_direct(
    const float* __restrict__ x, const float* __restrict__ wgt,
    float* __restrict__ out)
{
    const int ocpair = blockIdx.x, ht = blockIdx.y, b = blockIdx.z;
    const int oc0 = ocpair * 2, h0 = ht * 8;
    const int t = threadIdx.x, w = t & 127, hl = (t >> 7) * 4;
    __shared__ float sm[10][128];
    float acc[2][4];
    #pragma unroll
    for (int i = 0; i < 2; ++i)
        #pragma unroll
        for (int j = 0; j < 4; ++j) acc[i][j] = 0.f;
    const float* xb  = x + (size_t)b * C_ * H_ * W_;
    const float* wp0 = wgt + (size_t)oc0 * C_ * 9;
    const float* wp1 = wp0 + (size_t)C_ * 9;
    for (int ic = 0; ic < C_; ++ic) {
        const float* xc = xb + (size_t)ic * H_ * W_;
        __syncthreads();
        #pragma unroll
        for (int k = 0; k < 5; ++k) {
            int idx = t + k * 256, r = idx >> 7, c = idx & 127, gr = h0 - 1 + r;
            sm[r][c] = (gr >= 0 && gr < H_) ? xc[gr * W_ + c] : 0.f;
        }
        __syncthreads();
        float wa[9], wbv[9];
        #pragma unroll
        for (int qq = 0; qq < 9; ++qq) { wa[qq] = wp0[ic*9+qq]; wbv[qq] = wp1[ic*9+qq]; }
        float in[6][3];
        #pragma unroll
        for (int r = 0; r < 6; ++r) {
            int rr = hl + r;
            in[r][0] = (w > 0)   ? sm[rr][w-1] : 0.f;
            in[r][1] =             sm[rr][w];
            in[r][2] = (w < 127) ? sm[rr][w+1] : 0.f;
        }
        #pragma unroll
        for (int j = 0; j < 4; ++j)
            #pragma unroll
            for (int dh = 0; dh < 3; ++dh)
                #pragma unroll
                for (int dw = 0; dw < 3; ++dw) {
                    float v = in[j+dh][dw];
                    acc[0][j] = fmaf(v, wa[dh*3+dw], acc[0][j]);
                    acc[1][j] = fmaf(v, wbv[dh*3+dw], acc[1][j]);
                }
    }
    const bool win_w = (w >= 44 && w < 84);
    #pragma unroll
    for (int i = 0; i < 2; ++i) {
        float* ob = out + (((size_t)b * C_ + (oc0+i)) * H_ + h0) * (size_t)W_;
        #pragma unroll
        for (int j = 0; j < 4; ++j) {
            int h = h0 + hl + j;
            ob[(hl+j) * W_ + w] = (win_w && h >= 44 && h < 84) ? 0.f : acc[i][j];
        }
    }
}

extern "C" void kernel_launch(void* const* d_in, const int* in_sizes, int n_in,
                              void* d_out, int out_size, void* d_ws, size_t ws_size,
                              hipStream_t stream) {
    const float* x   = (const float*)d_in[0];
    const float* wgt = (const float*)d_in[1];
    float* out       = (float*)d_out;

    const size_t W_BYTES = 9 * 64 * 64 * 2;                        // 73,728
    if (ws_size >= W_BYTES) {
        uint16_t* Wb = (uint16_t*)d_ws;
        xform_weight<<<dim3(144), dim3(256), 0, stream>>>(wgt, Wb);
        conv_mfma<<<dim3(64, 16), dim3(256), 0, stream>>>(
            (const uint4*)Wb, x, out);
    } else {
        cropconv_direct<<<dim3(32, 16, 16), dim3(256), 0, stream>>>(x, wgt, out);
    }
}